// Round 13
// baseline (68.503 us; speedup 1.0000x reference)
//
#include <hip/hip_runtime.h>

using u32 = unsigned int;

typedef __attribute__((ext_vector_type(8))) _Float16 f16x8;
typedef __attribute__((ext_vector_type(4))) float    f32x4;

// ---------------------------------------------------------------------------
// prep 1: x (f32, 65536x256) -> f16 xh, same layout. 8 elems/thread.
// ---------------------------------------------------------------------------
__global__ __launch_bounds__(256) void cast_x_f16(const float4* __restrict__ x4,
                                                  uint4* __restrict__ o4) {
    int t = blockIdx.x * 256 + threadIdx.x;
    float4 a = x4[2 * t];
    float4 b = x4[2 * t + 1];
    union { f16x8 h; uint4 u; } cv;
    cv.h[0] = (_Float16)a.x; cv.h[1] = (_Float16)a.y;
    cv.h[2] = (_Float16)a.z; cv.h[3] = (_Float16)a.w;
    cv.h[4] = (_Float16)b.x; cv.h[5] = (_Float16)b.y;
    cv.h[6] = (_Float16)b.z; cv.h[7] = (_Float16)b.w;
    o4[t] = cv.u;
}

// ---------------------------------------------------------------------------
// prep 2: WcatT[n][kk] = s(i,kb) * W[c][(i^kb)*256 + u]   (f16, 1024x1024)
// sign bits packed: bit (4*i + kb) of 0x3950
// ---------------------------------------------------------------------------
__global__ __launch_bounds__(256) void build_wcatT(const float* __restrict__ W,
                                                   _Float16* __restrict__ Wt) {
    int t  = blockIdx.x * 256 + threadIdx.x;
    int n  = t >> 10, kk = t & 1023;
    int kb = n >> 8,  u  = n & 255;
    int i  = kk >> 8, c  = kk & 255;
    int j  = i ^ kb;
    float v = W[c * 1024 + j * 256 + u];
    if ((0x3950u >> (i * 4 + kb)) & 1u) v = -v;
    Wt[t] = (_Float16)v;
}

// ---------------------------------------------------------------------------
// GEMM, 8-phase m201-style schedule.  M=16384 N=1024 K=1024.
//   256x256 tile, BK=64 (16 K-tiles), K-split halves kh0/kh1 (32 K each).
//   LDS: 2 dbuf x { A-kh0 16K | A-kh1 16K | B-kh0 16K | B-kh1 16K } = 128 KB.
//   8 waves (2M x 4N), acc[8][4]. Per K-tile: 4 phases, each
//   {4-8 ds_read_b128; 1 half-tile stage (2 gload_lds); [VMW(4) at ph2/ph4];
//    barrier; lgkmcnt(0); 16 MFMA (setprio); barrier}.
//   Stages of tile v+1 issued during tile v; gates drain exactly what the
//   next phase pair reads. Never vmcnt(0) in steady state.
//   Swizzle (32-f16 rows, 4 chunks): phys = lg ^ (l15&3) ^ ((l15>>2)&3);
//   source pre-swizzled, LDS dest linear (gload_lds rule).
// ---------------------------------------------------------------------------
__device__ __forceinline__ void async16(const void* g, void* l) {
    __builtin_amdgcn_global_load_lds((const __attribute__((address_space(1))) u32*)g,
                                     (__attribute__((address_space(3))) u32*)l,
                                     16, 0, 0);
}

#define BARRIER() do { asm volatile("" ::: "memory"); \
                       __builtin_amdgcn_s_barrier(); \
                       asm volatile("" ::: "memory"); } while (0)

#define VMW(n)  asm volatile("s_waitcnt vmcnt(" #n ")" ::: "memory")
#define LGKM0() asm volatile("s_waitcnt lgkmcnt(0)" ::: "memory")
#define SB0()   __builtin_amdgcn_sched_barrier(0)

#define MFMA(av, bv, c) __builtin_amdgcn_mfma_f32_16x16x32_f16(av, bv, c, 0, 0, 0)

// 16-MFMA cluster for m-group G (frags G*4..G*4+3) x bf0..bf3
#define MFMA16(G) do { \
    __builtin_amdgcn_s_setprio(1); \
    acc[(G)*4+0][0]=MFMA(af0,bf0,acc[(G)*4+0][0]); acc[(G)*4+0][1]=MFMA(af0,bf1,acc[(G)*4+0][1]); \
    acc[(G)*4+0][2]=MFMA(af0,bf2,acc[(G)*4+0][2]); acc[(G)*4+0][3]=MFMA(af0,bf3,acc[(G)*4+0][3]); \
    acc[(G)*4+1][0]=MFMA(af1,bf0,acc[(G)*4+1][0]); acc[(G)*4+1][1]=MFMA(af1,bf1,acc[(G)*4+1][1]); \
    acc[(G)*4+1][2]=MFMA(af1,bf2,acc[(G)*4+1][2]); acc[(G)*4+1][3]=MFMA(af1,bf3,acc[(G)*4+1][3]); \
    acc[(G)*4+2][0]=MFMA(af2,bf0,acc[(G)*4+2][0]); acc[(G)*4+2][1]=MFMA(af2,bf1,acc[(G)*4+2][1]); \
    acc[(G)*4+2][2]=MFMA(af2,bf2,acc[(G)*4+2][2]); acc[(G)*4+2][3]=MFMA(af2,bf3,acc[(G)*4+2][3]); \
    acc[(G)*4+3][0]=MFMA(af3,bf0,acc[(G)*4+3][0]); acc[(G)*4+3][1]=MFMA(af3,bf1,acc[(G)*4+3][1]); \
    acc[(G)*4+3][2]=MFMA(af3,bf2,acc[(G)*4+3][2]); acc[(G)*4+3][3]=MFMA(af3,bf3,acc[(G)*4+3][3]); \
    __builtin_amdgcn_s_setprio(0); \
    __builtin_amdgcn_sched_barrier(0); \
} while (0)

// stage A K-half KH of K-tile T into buffer at f16-offset TB (2 gload_lds)
#define STAGE_A(T, KH, TB) do { \
    const _Float16* _s = gAs + (size_t)((T) >> 2) * 4194304 + ((T) & 3) * 64 + (KH) * 32; \
    _Float16* _d = lds + (TB) + (KH) * 8192 + tid * 8; \
    async16(_s, _d); \
    async16(_s + 32768, _d + 4096); \
} while (0)

// stage B K-half KH of K-tile T into buffer at f16-offset TB (2 gload_lds)
#define STAGE_B(T, KH, TB) do { \
    const _Float16* _s = gBs + (size_t)(T) * 64 + (KH) * 32; \
    _Float16* _d = lds + (TB) + 16384 + (KH) * 8192 + tid * 8; \
    async16(_s, _d); \
    async16(_s + 131072, _d + 4096); \
} while (0)

// read 4 A frags (m-group G, K-half KH) from dbuf DB
#define LDA4(G, KH, DB) do { \
    const _Float16* _a = lds + (DB) + (KH) * 8192 + aBase + (G) * 2048; \
    af0 = *(const f16x8*)(_a);        af1 = *(const f16x8*)(_a + 512); \
    af2 = *(const f16x8*)(_a + 1024); af3 = *(const f16x8*)(_a + 1536); \
} while (0)

// read 4 B frags (K-half KH) from dbuf DB
#define LDB4(KH, DB) do { \
    const _Float16* _b = lds + (DB) + 16384 + (KH) * 8192 + bBase; \
    bf0 = *(const f16x8*)(_b);        bf1 = *(const f16x8*)(_b + 512); \
    bf2 = *(const f16x8*)(_b + 1024); bf3 = *(const f16x8*)(_b + 1536); \
} while (0)

__global__ __launch_bounds__(512, 2) void ga_gemm(const _Float16* __restrict__ A,   // xh f16
                                                  const _Float16* __restrict__ Bt,  // WcatT
                                                  const float*  __restrict__ bias,
                                                  float* __restrict__ out) {
    __shared__ _Float16 lds[2 * 32768] __attribute__((aligned(16)));  // 128 KiB

    const int tid  = threadIdx.x;
    const int lane = tid & 63;
    const int wid  = tid >> 6;
    const int wm   = wid >> 2;          // 0..1  (M half of 256)
    const int wn   = wid & 3;           // 0..3  (N quarter of 256)
    const int l15  = lane & 15;
    const int lg   = lane >> 4;

    // XCD-aware bijective swizzle: 256 blocks, 8 XCDs, 32 contiguous each
    const int bid = blockIdx.x;
    const int swz = (bid & 7) * 32 + (bid >> 3);
    const int mt  = swz >> 2, nt = swz & 3;
    const int m0  = mt * 256,  n0 = nt * 256;

    // staging map: slot s in {tid, 512+tid} -> row s>>2 (0..255), chunk s&3;
    // source chunk pre-swizzled: (s&3) ^ (r&3) ^ ((r>>2)&3)  (same for both slots)
    const int r0   = tid >> 2;
    const int scol = ((tid & 3) ^ (r0 & 3) ^ ((r0 >> 2) & 3)) * 8;
    const _Float16* gAs = A  + (size_t)(m0 + r0) * 256  + scol;
    const _Float16* gBs = Bt + (size_t)(n0 + r0) * 1024 + scol;

    // fragment read bases (f16 units); phys chunk = lg ^ (l15&3) ^ ((l15>>2)&3)
    const int sw    = (l15 & 3) ^ ((l15 >> 2) & 3);
    const int aBase = (wm * 128 + l15) * 32 + ((lg ^ sw) * 8);
    const int bBase = (wn * 64  + l15) * 32 + ((lg ^ sw) * 8);

    f32x4 acc[8][4] = {};
    f16x8 af0, af1, af2, af3, bf0, bf1, bf2, bf3;

    // prologue: stage tile 0 (A0,B0,A1,B1 -> dbuf0, 8 loads); drain kh0 pair
    STAGE_A(0, 0, 0);  STAGE_B(0, 0, 0);
    STAGE_A(0, 1, 0);  STAGE_B(0, 1, 0);
    VMW(4);                               // A-kh0, B-kh0 landed
    BARRIER();

    // steady tiles 0..14: stage tile v+1 during tile v; VMW(4) at ph2/ph4
#pragma unroll 1
    for (int v = 0; v < 15; ++v) {
        const int db = (v & 1) << 15;
        const int tb = db ^ 32768;
        // ph1: kh0, group0 (+B kh0) ; stage A-kh0(v+1)
        LDA4(0, 0, db);  LDB4(0, db);  STAGE_A(v + 1, 0, tb);
        BARRIER();  LGKM0();  SB0();
        MFMA16(0);
        BARRIER();
        // ph2: kh0, group1 ; stage B-kh0(v+1) ; gate (drains A1,B1 of v)
        LDA4(1, 0, db);  STAGE_B(v + 1, 0, tb);  VMW(4);
        BARRIER();  LGKM0();  SB0();
        MFMA16(1);
        BARRIER();
        // ph3: kh1, group0 (+B kh1) ; stage A-kh1(v+1)
        LDA4(0, 1, db);  LDB4(1, db);  STAGE_A(v + 1, 1, tb);
        BARRIER();  LGKM0();  SB0();
        MFMA16(0);
        BARRIER();
        // ph4: kh1, group1 ; stage B-kh1(v+1) ; gate (drains A0,B0 of v+1)
        LDA4(1, 1, db);  STAGE_B(v + 1, 1, tb);  VMW(4);
        BARRIER();  LGKM0();  SB0();
        MFMA16(1);
        BARRIER();
    }

    // tile 15 (db = 32768): no staging; drain remaining at ph2
    {
        const int db = 32768;
        LDA4(0, 0, db);  LDB4(0, db);
        BARRIER();  LGKM0();  SB0();
        MFMA16(0);
        BARRIER();
        LDA4(1, 0, db);  VMW(0);
        BARRIER();  LGKM0();  SB0();
        MFMA16(1);
        BARRIER();
        LDA4(0, 1, db);  LDB4(1, db);
        BARRIER();  LGKM0();  SB0();
        MFMA16(0);
        BARRIER();
        LDA4(1, 1, db);
        LGKM0();  SB0();
        MFMA16(1);
    }

    // epilogue: C/D layout col=lane&15 (n), row=(lane>>4)*4+r (m)
    const size_t outBase = (size_t)nt * 16384 * 256;   // blade kb == nt
    const int ucol = wn * 64 + l15;
    float bv[4];
#pragma unroll
    for (int fn = 0; fn < 4; ++fn) bv[fn] = bias[nt * 256 + ucol + fn * 16];
#pragma unroll
    for (int fm = 0; fm < 8; ++fm) {
        const int m = m0 + wm * 128 + fm * 16 + lg * 4;
#pragma unroll
        for (int r = 0; r < 4; ++r) {
            float* op = out + outBase + (size_t)(m + r) * 256;
#pragma unroll
            for (int fn = 0; fn < 4; ++fn)
                op[ucol + fn * 16] = acc[fm][fn][r] + bv[fn];
        }
    }
}

// ---------------------------------------------------------------------------
extern "C" void kernel_launch(void* const* d_in, const int* in_sizes, int n_in,
                              void* d_out, int out_size, void* d_ws, size_t ws_size,
                              hipStream_t stream) {
    (void)in_sizes; (void)n_in; (void)out_size; (void)ws_size;
    const float* x = (const float*)d_in[0];   // (65536, 256)
    const float* W = (const float*)d_in[1];   // (256, 1024)
    const float* b = (const float*)d_in[2];   // (1024,)
    float* out = (float*)d_out;               // (65536, 256)

    _Float16* Wt = (_Float16*)d_ws;                                   // 2 MB
    _Float16* xh = (_Float16*)((char*)d_ws + (size_t)(2u << 20));     // 32 MB

    build_wcatT<<<4096, 256, 0, stream>>>(W, Wt);
    cast_x_f16<<<8192, 256, 0, stream>>>((const float4*)x, (uint4*)xh);
    ga_gemm<<<256, 512, 0, stream>>>(xh, Wt, b, out);
}

// Round 15
// 51.956 us; speedup vs baseline: 1.3185x; 1.3185x over previous
//
#include <hip/hip_runtime.h>

using u32 = unsigned int;

typedef __attribute__((ext_vector_type(8))) _Float16 f16x8;
typedef __attribute__((ext_vector_type(4))) float    f32x4;

// ---------------------------------------------------------------------------
// prep: WcatT[n][kk] = s(i,kb) * W[c][(i^kb)*256 + u]   (f16, 1024x1024)
// sign bits packed: bit (4*i + kb) of 0x3950
// ---------------------------------------------------------------------------
__global__ __launch_bounds__(256) void build_wcatT(const float* __restrict__ W,
                                                   _Float16* __restrict__ Wt) {
    int t  = blockIdx.x * 256 + threadIdx.x;
    int n  = t >> 10, kk = t & 1023;
    int kb = n >> 8,  u  = n & 255;
    int i  = kk >> 8, c  = kk & 255;
    int j  = i ^ kb;
    float v = W[c * 1024 + j * 256 + u];
    if ((0x3950u >> (i * 4 + kb)) & 1u) v = -v;
    Wt[t] = (_Float16)v;
}

// ---------------------------------------------------------------------------
// GEMM, 8-phase schedule + fused f32->f16 A-cast.  M=16384 N=1024 K=1024.
//   256x256 tile, BK=64 (16 K-tiles), kh0/kh1 K-halves.
//   LDS per dbuf (f16 offs): A-kh0 @0, A-kh1 @8192, B-kh0 @16384, B-kh1 @24576.
//   2 dbufs (stride 32768 f16) = 128 KiB. 8 waves (2M x 4N), acc[8][4].
//   Per K-tile: 4 phases {ds_reads; issue(A GL16 / B gload_lds); VMW(6);
//     [cvt+swizzled ds_write of A half]; barrier; lgkm0; 16 MFMA; barrier}.
//   Vmem ledger (12 ops/tile): entering tile v = [A-k1(v):4, B-kh1(v):2];
//   VMW(6) each phase drains exactly the next-needed group. Never vmcnt(0)
//   in steady state.  Swizzle both sides: phys_chunk = c ^ ((row>>1)&3).
//   FIX vs R14: ISSUE_A blade decomposition — kk = U*64+KH*32 lives in x-row
//   blade (U>>2)*16384, channel (U&3)*64+KH*32 (NOT a linear column walk).
// ---------------------------------------------------------------------------
__device__ __forceinline__ void async16(const void* g, void* l) {
    __builtin_amdgcn_global_load_lds((const __attribute__((address_space(1))) u32*)g,
                                     (__attribute__((address_space(3))) u32*)l,
                                     16, 0, 0);
}

#define BARRIER() do { asm volatile("" ::: "memory"); \
                       __builtin_amdgcn_s_barrier(); \
                       asm volatile("" ::: "memory"); } while (0)

#define VMW(n)  asm volatile("s_waitcnt vmcnt(" #n ")" ::: "memory")
#define LGKM0() asm volatile("s_waitcnt lgkmcnt(0)" ::: "memory")
#define SB0()   __builtin_amdgcn_sched_barrier(0)

#define GL16(dst, ptr, off) \
    asm volatile("global_load_dwordx4 %0, %1, off offset:" #off \
                 : "=v"(dst) : "v"(ptr))

#define MFMA(av, bv, c) __builtin_amdgcn_mfma_f32_16x16x32_f16(av, bv, c, 0, 0, 0)

// 16-MFMA cluster for m-group G (frags G*4..G*4+3) x bf0..bf3
#define MFMA16(G) do { \
    __builtin_amdgcn_s_setprio(1); \
    acc[(G)*4+0][0]=MFMA(af0,bf0,acc[(G)*4+0][0]); acc[(G)*4+0][1]=MFMA(af0,bf1,acc[(G)*4+0][1]); \
    acc[(G)*4+0][2]=MFMA(af0,bf2,acc[(G)*4+0][2]); acc[(G)*4+0][3]=MFMA(af0,bf3,acc[(G)*4+0][3]); \
    acc[(G)*4+1][0]=MFMA(af1,bf0,acc[(G)*4+1][0]); acc[(G)*4+1][1]=MFMA(af1,bf1,acc[(G)*4+1][1]); \
    acc[(G)*4+1][2]=MFMA(af1,bf2,acc[(G)*4+1][2]); acc[(G)*4+1][3]=MFMA(af1,bf3,acc[(G)*4+1][3]); \
    acc[(G)*4+2][0]=MFMA(af2,bf0,acc[(G)*4+2][0]); acc[(G)*4+2][1]=MFMA(af2,bf1,acc[(G)*4+2][1]); \
    acc[(G)*4+2][2]=MFMA(af2,bf2,acc[(G)*4+2][2]); acc[(G)*4+2][3]=MFMA(af2,bf3,acc[(G)*4+2][3]); \
    acc[(G)*4+3][0]=MFMA(af3,bf0,acc[(G)*4+3][0]); acc[(G)*4+3][1]=MFMA(af3,bf1,acc[(G)*4+3][1]); \
    acc[(G)*4+3][2]=MFMA(af3,bf2,acc[(G)*4+3][2]); acc[(G)*4+3][3]=MFMA(af3,bf3,acc[(G)*4+3][3]); \
    __builtin_amdgcn_s_setprio(0); \
    __builtin_amdgcn_sched_barrier(0); \
} while (0)

// issue A f32 loads for K-tile U, K-half KH: rows (ar, ar+128) x 32B -> 4 GL16
// blade = U>>2 (x-row offset (U>>2)*16384*256 elems); channel = (U&3)*64+KH*32
#define ISSUE_A(U, KH, R) do { \
    const float* _p = pA + (size_t)((U) >> 2) * 4194304 + ((U) & 3) * 64 + (KH) * 32; \
    GL16(R##0, _p, 0); GL16(R##1, _p, 16); \
    const float* _q = _p + 32768; \
    GL16(R##2, _q, 0); GL16(R##3, _q, 16); \
} while (0)

// cvt 16 f32 -> 2 swizzled ds_write_b128 into A region at f16-offset OFF
#define WRITE_A(OFF, R) do { \
    f16x8 h0, h1; \
    h0[0]=(_Float16)R##0[0]; h0[1]=(_Float16)R##0[1]; h0[2]=(_Float16)R##0[2]; h0[3]=(_Float16)R##0[3]; \
    h0[4]=(_Float16)R##1[0]; h0[5]=(_Float16)R##1[1]; h0[6]=(_Float16)R##1[2]; h0[7]=(_Float16)R##1[3]; \
    h1[0]=(_Float16)R##2[0]; h1[1]=(_Float16)R##2[1]; h1[2]=(_Float16)R##2[2]; h1[3]=(_Float16)R##2[3]; \
    h1[4]=(_Float16)R##3[0]; h1[5]=(_Float16)R##3[1]; h1[6]=(_Float16)R##3[2]; h1[7]=(_Float16)R##3[3]; \
    _Float16* _wp = lds + (OFF) + aw0; \
    *(f16x8*)(_wp) = h0; \
    *(f16x8*)(_wp + 4096) = h1; \
} while (0)

// stage B K-tile U, K-half KH into dbuf at f16-offset TB (2 gload_lds)
#define STAGE_B(U, KH, TB) do { \
    const _Float16* _s = gBs + (U) * 64 + (KH) * 32; \
    _Float16* _d = lds + (TB) + 16384 + (KH) * 8192 + tid * 8; \
    async16(_s, _d); \
    async16(_s + 131072, _d + 4096); \
} while (0)

// read 4 A frags (m-group G) from A region at f16-offset BASE
#define LDA4(G, BASE) do { \
    const _Float16* _a = lds + (BASE) + aoff + (G) * 2048; \
    af0 = *(const f16x8*)(_a);        af1 = *(const f16x8*)(_a + 512); \
    af2 = *(const f16x8*)(_a + 1024); af3 = *(const f16x8*)(_a + 1536); \
} while (0)

// read 4 B frags from B region at f16-offset BASE
#define LDB4(BASE) do { \
    const _Float16* _b = lds + (BASE) + boff; \
    bf0 = *(const f16x8*)(_b);        bf1 = *(const f16x8*)(_b + 512); \
    bf2 = *(const f16x8*)(_b + 1024); bf3 = *(const f16x8*)(_b + 1536); \
} while (0)

__global__ __launch_bounds__(512, 2) void ga_gemm(const float* __restrict__ A,    // x f32
                                                  const _Float16* __restrict__ Bt,// WcatT
                                                  const float*  __restrict__ bias,
                                                  float* __restrict__ out) {
    __shared__ _Float16 lds[2 * 32768] __attribute__((aligned(16)));  // 128 KiB

    const int tid  = threadIdx.x;
    const int lane = tid & 63;
    const int wid  = tid >> 6;
    const int wm   = wid >> 2;          // 0..1  (M half of 256)
    const int wn   = wid & 3;           // 0..3  (N quarter of 256)
    const int l15  = lane & 15;
    const int lg   = lane >> 4;

    // XCD-aware bijective swizzle: 256 blocks, 8 XCDs, 32 contiguous each
    const int bid = blockIdx.x;
    const int swz = (bid & 7) * 32 + (bid >> 3);
    const int mt  = swz >> 2, nt = swz & 3;
    const int m0  = mt * 256,  n0 = nt * 256;

    // A reg-staging: 4 threads/row; slots rows (ar, ar+128), 32B f32 chunk ac
    const int ar = tid >> 2, ac = tid & 3;
    const float* pA = A + (size_t)(m0 + ar) * 256 + ac * 8;
    const int aw0 = ar * 32 + (ac ^ ((ar >> 1) & 3)) * 8;   // f16 units (+4096 row+128)

    // B staging (slot s -> row s>>2, chunk s&3; source chunk pre-swizzled)
    const int r0 = tid >> 2;
    const int g0 = (tid & 3) ^ ((r0 >> 1) & 3);
    const _Float16* gBs = Bt + (size_t)(n0 + r0) * 1024 + g0 * 8;
    // rows +128 at gBs + 131072 (same swizzle phase)

    // fragment ds_read offsets (f16 units); phys chunk = lg ^ ((row>>1)&3)
    const int sc   = lg ^ ((l15 >> 1) & 3);
    const int aoff = (wm * 128 + l15) * 32 + sc * 8;
    const int boff = (wn * 64  + l15) * 32 + sc * 8;

    f32x4 acc[8][4] = {};
    f32x4 u0, u1, u2, u3, v0, v1, v2, v3;
    f16x8 af0, af1, af2, af3, bf0, bf1, bf2, bf3;

    // prologue: tile 0 -> buf0; queue [Ak0:4, Bkh0:2, Ak1:4, Bkh1:2]
    ISSUE_A(0, 0, u);
    STAGE_B(0, 0, 0);
    ISSUE_A(0, 1, v);
    STAGE_B(0, 1, 0);
    VMW(6);  SB0();                 // drains A-k0(0), B-kh0(0)
    WRITE_A(0, u);                  // A-kh0(0) -> buf0
    LGKM0();
    BARRIER();
    // invariant entering tile 0: [A-k1(0) in v:4, B-kh1(0):2]

#pragma unroll 1
    for (int t = 0; t < 15; ++t) {
        const int db = (t & 1) << 15;
        const int tb = db ^ 32768;
        // ph1: reads kh0 G0 + B-kh0; issue A-k0(t+1); write A-k1(t) -> db+8192
        LDA4(0, db);  LDB4(db + 16384);
        ISSUE_A(t + 1, 0, u);
        VMW(6);  SB0();             // drains A-k1(t) regs (v)
        WRITE_A(db + 8192, v);
        BARRIER();  LGKM0();  SB0();
        MFMA16(0);
        BARRIER();
        // ph2: reads kh0 G1; issue B-kh0(t+1)
        LDA4(1, db);
        STAGE_B(t + 1, 0, tb);
        VMW(6);                     // drains B-kh1(t) (read next phase)
        BARRIER();  LGKM0();  SB0();
        MFMA16(1);
        BARRIER();
        // ph3: reads kh1 G0 + B-kh1; issue A-k1(t+1); write A-k0(t+1) -> tb
        LDA4(0, db + 8192);  LDB4(db + 24576);
        ISSUE_A(t + 1, 1, v);
        VMW(6);  SB0();             // drains A-k0(t+1) regs (u)
        WRITE_A(tb, u);
        BARRIER();  LGKM0();  SB0();
        MFMA16(0);
        BARRIER();
        // ph4: reads kh1 G1; issue B-kh1(t+1)
        LDA4(1, db + 8192);
        STAGE_B(t + 1, 1, tb);
        VMW(6);                     // drains B-kh0(t+1) (read ph1 of t+1)
        BARRIER();  LGKM0();  SB0();
        MFMA16(1);
        BARRIER();
    }

    // tile 15 (db = 32768): no staging
    {
        const int db = 32768;
        LDA4(0, db);  LDB4(db + 16384);
        VMW(2);  SB0();             // drains A-k1(15) regs (v)
        WRITE_A(db + 8192, v);
        BARRIER();  LGKM0();  SB0();
        MFMA16(0);
        BARRIER();
        LDA4(1, db);
        VMW(0);                     // drains B-kh1(15)
        BARRIER();  LGKM0();  SB0();
        MFMA16(1);
        BARRIER();
        LDA4(0, db + 8192);  LDB4(db + 24576);
        BARRIER();  LGKM0();  SB0();
        MFMA16(0);
        BARRIER();
        LDA4(1, db + 8192);
        LGKM0();  SB0();
        MFMA16(1);
    }

    // epilogue: C/D layout col=lane&15 (n), row=(lane>>4)*4+r (m)
    const size_t outBase = (size_t)nt * 16384 * 256;   // blade kb == nt
    const int ucol = wn * 64 + l15;
    float bv[4];
#pragma unroll
    for (int fn = 0; fn < 4; ++fn) bv[fn] = bias[nt * 256 + ucol + fn * 16];
#pragma unroll
    for (int fm = 0; fm < 8; ++fm) {
        const int m = m0 + wm * 128 + fm * 16 + lg * 4;
#pragma unroll
        for (int r = 0; r < 4; ++r) {
            float* op = out + outBase + (size_t)(m + r) * 256;
#pragma unroll
            for (int fn = 0; fn < 4; ++fn)
                op[ucol + fn * 16] = acc[fm][fn][r] + bv[fn];
        }
    }
}

// ---------------------------------------------------------------------------
extern "C" void kernel_launch(void* const* d_in, const int* in_sizes, int n_in,
                              void* d_out, int out_size, void* d_ws, size_t ws_size,
                              hipStream_t stream) {
    (void)in_sizes; (void)n_in; (void)out_size; (void)ws_size;
    const float* x = (const float*)d_in[0];   // (65536, 256)
    const float* W = (const float*)d_in[1];   // (256, 1024)
    const float* b = (const float*)d_in[2];   // (1024,)
    float* out = (float*)d_out;               // (65536, 256)

    _Float16* Wt = (_Float16*)d_ws;           // 2 MB

    build_wcatT<<<4096, 256, 0, stream>>>(W, Wt);
    ga_gemm<<<256, 512, 0, stream>>>(x, Wt, b, out);
}